// Round 2
// baseline (1377.352 us; speedup 1.0000x reference)
//
#include <hip/hip_runtime.h>
#include <stdint.h>

#define H 512
#define KAUG 528
#define KT_N 33            // K tiles of 16 (528/16) -- encoder bf16 path
#define LROW 536           // LDS row stride in shorts (16B aligned, 2-way bank alias = free)
#define NROW 32
#define WMAT_ELEMS (16 * KT_N * 4 * 512)   // encoder: 16 ntL * 33 kt * 4 gates * 512 = 1,081,344
#define WMAT8_BYTES 1081344                // decoder fp8: 16 ntL * (16*4096 + 2048) = 1,081,344
#define NTL8_BYTES 67584                   // per ntL: 16 kt-pairs*4g*1024B + tail 4g*512B
#define T_DEC 32
#define B_TOT 4096
#define SCL 0.015625f                      // 1/64: undo weight pre-scale after accumulation

typedef __attribute__((ext_vector_type(8))) short short8;
typedef __attribute__((ext_vector_type(16))) float floatx16;
typedef __attribute__((ext_vector_type(2))) float float2v;
typedef __attribute__((ext_vector_type(4))) unsigned int uint4v;
typedef __attribute__((ext_vector_type(2))) unsigned int uint2v;

__device__ __forceinline__ unsigned short f2bf(float x) {
  union { float f; unsigned int u; } v; v.f = x;
  unsigned int u = v.u;
  return (unsigned short)((u + 0x7FFFu + ((u >> 16) & 1u)) >> 16);
}
__device__ __forceinline__ float bf2f(unsigned short s) {
  union { unsigned int u; float f; } v; v.u = ((unsigned int)s) << 16;
  return v.f;
}
__device__ __forceinline__ float rcpf(float x) { return __builtin_amdgcn_rcpf(x); }
__device__ __forceinline__ float sigm(float x) { return rcpf(1.0f + __expf(-x)); }
__device__ __forceinline__ float tanh_f(float x) {
  return 1.0f - 2.0f * rcpf(1.0f + __expf(2.0f * x));
}

// ---- f32 -> OCP e4m3fn (RNE, saturating). Runs once in prep; exactness not speed. ----
__device__ __forceinline__ unsigned char f2e4m3(float f) {
  unsigned int u = __float_as_uint(f);
  unsigned int s = (u >> 24) & 0x80u;
  float a = fabsf(f);
  if (!(a < 464.0f)) return (unsigned char)(s | 0x7Eu);   // saturate to 448
  if (a < 0.0009765625f) return (unsigned char)s;         // < 2^-10 (half min denorm) -> 0
  int e = (int)((__float_as_uint(a) >> 23) & 0xFF) - 127; // floor(log2 a)
  int q = (e < -6 ? -6 : e) - 3;                          // quantum exponent
  float sc  = __uint_as_float((unsigned int)((127 - q) << 23)); // 2^-q
  float isc = __uint_as_float((unsigned int)((127 + q) << 23)); // 2^q
  float n = rintf(a * sc);                                // RNE onto the e4m3 grid
  float r = n * isc;
  if (r == 0.0f) return (unsigned char)s;
  int e2 = (int)((__float_as_uint(r) >> 23) & 0xFF) - 127;
  unsigned int bits;
  if (e2 < -6) {
    bits = (unsigned int)(r * 512.0f + 0.5f);             // denormal: r = m * 2^-9 exactly
  } else {
    float msc = __uint_as_float((unsigned int)((127 - (e2 - 3)) << 23)); // 2^(3-e2)
    unsigned int mant = (unsigned int)(r * msc + 0.5f);   // in [8,16); carry handled via e2
    bits = ((unsigned int)(e2 + 7) << 3) | (mant & 7u);
  }
  return (unsigned char)(s | bits);
}

// ---- 8x e4m3fn (2 dwords) -> 8x bf16. fp8->f32 exact; f32->bf16 truncation exact (3<=7 mant bits).
__device__ __forceinline__ short8 dq8(unsigned int d0, unsigned int d1) {
  float2v p0 = __builtin_amdgcn_cvt_pk_f32_fp8(d0, false);
  float2v p1 = __builtin_amdgcn_cvt_pk_f32_fp8(d0, true);
  float2v p2 = __builtin_amdgcn_cvt_pk_f32_fp8(d1, false);
  float2v p3 = __builtin_amdgcn_cvt_pk_f32_fp8(d1, true);
  union { unsigned int u[4]; short8 s; } r;
  r.u[0] = __builtin_amdgcn_perm(__float_as_uint(p0[1]), __float_as_uint(p0[0]), 0x07060302u);
  r.u[1] = __builtin_amdgcn_perm(__float_as_uint(p1[1]), __float_as_uint(p1[0]), 0x07060302u);
  r.u[2] = __builtin_amdgcn_perm(__float_as_uint(p2[1]), __float_as_uint(p2[0]), 0x07060302u);
  r.u[3] = __builtin_amdgcn_perm(__float_as_uint(p3[1]), __float_as_uint(p3[0]), 0x07060302u);
  return r.s;
}

// ---------------- prep (encoder, bf16): augmented tile-packed weights -------------
// W_aug[n][ka]: ka<512 -> Wh[n][ka]; 512..515 -> Wi[n][ka-512]; 516 -> b[n]; else 0
//   idx = ((ntL*33 + kt)*4 + g)*512 + lanep*8 + ks
__global__ void prep_weights(
    const float* __restrict__ Wh_s, const float* __restrict__ Wi_s, const float* __restrict__ b_s,
    const float* __restrict__ Wh_p, const float* __restrict__ Wi_p, const float* __restrict__ b_p,
    short* __restrict__ wpack)
{
  int idx = blockIdx.x * 256 + threadIdx.x;
  const int per = 2048 * KAUG;
  if (idx >= 2 * per) return;
  int mat = idx / per;
  int rem = idx - mat * per;
  int n = rem / KAUG;
  int ka = rem - n * KAUG;
  const float* Wh = mat ? Wh_p : Wh_s;
  const float* Wi = mat ? Wi_p : Wi_s;
  const float* bb = mat ? b_p  : b_s;
  float v;
  if (ka < 512)      v = Wh[n * 512 + ka];
  else if (ka < 516) v = Wi[n * 4 + (ka - 512)];
  else if (ka == 516) v = bb[n];
  else               v = 0.0f;
  int g = n >> 9, ntL = (n >> 5) & 15, ni = n & 31;
  int kt = ka >> 4, kh = (ka >> 3) & 1, ks = ka & 7;
  int lanep = kh * 32 + ni;
  wpack[(size_t)mat * WMAT_ELEMS +
        (((((size_t)ntL * KT_N + kt) * 4 + g) << 9) + (lanep << 3) + ks)] = (short)f2bf(v);
}

// ---------------- prep (decoder, fp8): kt-pair packed, weights pre-scaled x64 ------
// Per ntL: [p=0..15: 4 gates x 64 lanes x 16B (kt-pair)] then [tail kt=32: 4 gates x 64 lanes x 8B]
__global__ void prep_fp8(
    const float* __restrict__ Wh_d, const float* __restrict__ Wi_d, const float* __restrict__ b_d,
    const float* __restrict__ Wh_i, const float* __restrict__ Wi_i, const float* __restrict__ b_i,
    unsigned char* __restrict__ wpack8)
{
  int idx = blockIdx.x * 256 + threadIdx.x;      // one output byte per thread
  if (idx >= 2 * WMAT8_BYTES) return;
  int mat = idx / WMAT8_BYTES;
  int rem = idx - mat * WMAT8_BYTES;
  int ntL = rem / NTL8_BYTES;
  int off = rem - ntL * NTL8_BYTES;
  int g, lane, kt, ks;
  if (off < 65536) {
    int p = off >> 12;
    g = (off >> 10) & 3;
    lane = (off >> 4) & 63;
    int j = off & 15;
    kt = 2 * p + (j >> 3);
    ks = j & 7;
  } else {
    int t = off - 65536;
    g = t >> 9;
    lane = (t >> 3) & 63;
    ks = t & 7;
    kt = 32;
  }
  int n = g * 512 + ntL * 32 + (lane & 31);
  int ka = kt * 16 + (lane >> 5) * 8 + ks;
  const float* Wh = mat ? Wh_i : Wh_d;
  const float* Wi = mat ? Wi_i : Wi_d;
  const float* bb = mat ? b_i  : b_d;
  float v;
  if (ka < 512)       v = Wh[n * 512 + ka];
  else if (ka < 516)  v = Wi[n * 4 + (ka - 512)];
  else if (ka == 516) v = bb[n];
  else                v = 0.0f;
  wpack8[idx] = f2e4m3(v * 64.0f);
}

// ---------------- encoder LSTM step (bf16 weights), unchanged ----------------------
__device__ __forceinline__ void lstm_step_mfma(
    const short* hl, const short* __restrict__ wm,
    int lane, int wv, float c_reg[16], float hnew[16])
{
  int arow = lane & 31, ahalf = lane >> 5;
  const short* aptr = hl + arow * LROW + ahalf * 8;
  const short* bp = wm + (size_t)wv * (KT_N * 4 * 512) + (lane << 3);
  floatx16 ai = (floatx16)0.0f, af = (floatx16)0.0f, ag = (floatx16)0.0f, ao = (floatx16)0.0f;
  #pragma unroll 3
  for (int kt = 0; kt < KT_N; ++kt) {
    short8 a  = *(const short8*)(aptr + kt * 16);
    short8 b0 = *(const short8*)(bp);
    short8 b1 = *(const short8*)(bp + 512);
    short8 b2 = *(const short8*)(bp + 1024);
    short8 b3 = *(const short8*)(bp + 1536);
    bp += 2048;
    ai = __builtin_amdgcn_mfma_f32_32x32x16_bf16(a, b0, ai, 0, 0, 0);
    af = __builtin_amdgcn_mfma_f32_32x32x16_bf16(a, b1, af, 0, 0, 0);
    ag = __builtin_amdgcn_mfma_f32_32x32x16_bf16(a, b2, ag, 0, 0, 0);
    ao = __builtin_amdgcn_mfma_f32_32x32x16_bf16(a, b3, ao, 0, 0, 0);
  }
  #pragma unroll
  for (int r = 0; r < 16; ++r) {
    float si = sigm(ai[r]);
    float sf = sigm(af[r]);
    float tg = tanh_f(ag[r]);
    float so = sigm(ao[r]);
    float cn = sf * c_reg[r] + si * tg;
    c_reg[r] = cn;
    hnew[r] = so * tanh_f(cn);
  }
}

// ---------------- decoder LSTM step (fp8 weights, in-register dequant) -------------
__device__ __forceinline__ void lstm_step_mfma_fp8(
    const short* hl, const unsigned char* __restrict__ wmb,
    int lane, int wv, float c_reg[16], float hnew[16])
{
  int arow = lane & 31, ahalf = lane >> 5;
  const short* aptr = hl + arow * LROW + ahalf * 8;
  const unsigned char* base = wmb + (size_t)wv * NTL8_BYTES;
  const uint4v* bp = (const uint4v*)(base + (lane << 4));
  floatx16 ai = (floatx16)0.0f, af = (floatx16)0.0f, ag = (floatx16)0.0f, ao = (floatx16)0.0f;
  #pragma unroll 1
  for (int p = 0; p < 16; ++p) {
    uint4v di = bp[0];     // gate i, kt-pair (16 fp8)   +0    B
    uint4v df = bp[64];    // gate f                     +1024 B (imm)
    uint4v dg = bp[128];   // gate g                     +2048 B (imm)
    uint4v dd = bp[192];   // gate o                     +3072 B (imm)
    short8 a0 = *(const short8*)(aptr + p * 32);
    short8 a1 = *(const short8*)(aptr + p * 32 + 16);
    bp += 256;
    ai = __builtin_amdgcn_mfma_f32_32x32x16_bf16(a0, dq8(di[0], di[1]), ai, 0, 0, 0);
    af = __builtin_amdgcn_mfma_f32_32x32x16_bf16(a0, dq8(df[0], df[1]), af, 0, 0, 0);
    ag = __builtin_amdgcn_mfma_f32_32x32x16_bf16(a0, dq8(dg[0], dg[1]), ag, 0, 0, 0);
    ao = __builtin_amdgcn_mfma_f32_32x32x16_bf16(a0, dq8(dd[0], dd[1]), ao, 0, 0, 0);
    ai = __builtin_amdgcn_mfma_f32_32x32x16_bf16(a1, dq8(di[2], di[3]), ai, 0, 0, 0);
    af = __builtin_amdgcn_mfma_f32_32x32x16_bf16(a1, dq8(df[2], df[3]), af, 0, 0, 0);
    ag = __builtin_amdgcn_mfma_f32_32x32x16_bf16(a1, dq8(dg[2], dg[3]), ag, 0, 0, 0);
    ao = __builtin_amdgcn_mfma_f32_32x32x16_bf16(a1, dq8(dd[2], dd[3]), ao, 0, 0, 0);
  }
  { // tail kt = 32 (ka 512..527: Wi cols, bias, zeros) -- all A reads stay in-row
    const uint2v* tp = (const uint2v*)(base + 65536 + (lane << 3));
    uint2v ti = tp[0], tf = tp[64], tg = tp[128], td = tp[192];
    short8 a0 = *(const short8*)(aptr + 512);
    ai = __builtin_amdgcn_mfma_f32_32x32x16_bf16(a0, dq8(ti[0], ti[1]), ai, 0, 0, 0);
    af = __builtin_amdgcn_mfma_f32_32x32x16_bf16(a0, dq8(tf[0], tf[1]), af, 0, 0, 0);
    ag = __builtin_amdgcn_mfma_f32_32x32x16_bf16(a0, dq8(tg[0], tg[1]), ag, 0, 0, 0);
    ao = __builtin_amdgcn_mfma_f32_32x32x16_bf16(a0, dq8(td[0], td[1]), ao, 0, 0, 0);
  }
  #pragma unroll
  for (int r = 0; r < 16; ++r) {
    float si = sigm(ai[r] * SCL);       // undo x64 weight pre-scale here (4 muls/r)
    float sf = sigm(af[r] * SCL);
    float tg = tanh_f(ag[r] * SCL);
    float so = sigm(ao[r] * SCL);
    float cn = sf * c_reg[r] + si * tg;
    c_reg[r] = cn;
    hnew[r] = so * tanh_f(cn);
  }
}

__device__ __forceinline__ void write_h(short* hl, int lane, int wv, const float hnew[16]) {
  int arow = lane & 31, ahalf = lane >> 5;
  int col = (wv << 5) + arow;
  #pragma unroll
  for (int r = 0; r < 16; ++r) {
    int row = (r & 3) + ((r >> 2) << 3) + (ahalf << 2);
    hl[row * LROW + col] = (short)f2bf(hnew[r]);
  }
}

// ---------------- encoder: blocks 0..255 -> (enc, row-group) via XCD swizzle --
__global__ __launch_bounds__(1024) void lstm_encoder(
    const float* __restrict__ speed, const float* __restrict__ pos,
    const short* __restrict__ wpack,
    short* __restrict__ h_enc, float* __restrict__ c_enc)
{
  __shared__ short hl[NROW * LROW];
  int tid = threadIdx.x;
  int b = blockIdx.x;
  int xcd = b & 7, slot = b >> 3;
  int enc = xcd >> 2;               // XCDs 0-3: speed, 4-7: pos (L2 locality)
  int rg = slot * 4 + (xcd & 3);    // 0..127
  int r0 = rg * 32;
  const float* xin = enc ? pos : speed;
  const short* wm = wpack + (size_t)enc * WMAT_ELEMS;

  for (int i = tid; i < NROW * LROW; i += 1024) hl[i] = 0;
  __syncthreads();
  if (tid < 32) hl[tid * LROW + 516] = (short)0x3F80;   // bias lane = 1.0
  if (tid < 128) {
    int r = tid >> 2, c = tid & 3;
    hl[r * LROW + 512 + c] = (short)f2bf(xin[(r0 + r) * 64 + c]);   // x_0
  }
  __syncthreads();

  int lane = tid & 63, wv = tid >> 6;   // wv in [0,16)
  float c_reg[16];
  #pragma unroll
  for (int r = 0; r < 16; ++r) c_reg[r] = 0.0f;
  float hnew[16];

  for (int t = 0; t < 16; ++t) {
    lstm_step_mfma(hl, wm, lane, wv, c_reg, hnew);
    __syncthreads();
    write_h(hl, lane, wv, hnew);
    if (t < 15 && tid < 128) {
      int r = tid >> 2, c = tid & 3;
      hl[r * LROW + 512 + c] = (short)f2bf(xin[(r0 + r) * 64 + (t + 1) * 4 + c]);
    }
    __syncthreads();
  }

  for (int i = tid; i < 32 * 512; i += 1024) {
    int r = i >> 9, k = i & 511;
    h_enc[((size_t)(enc * B_TOT + r0 + r) << 9) + k] = hl[r * LROW + k];
  }
  int arow = lane & 31, ahalf = lane >> 5;
  int col = (wv << 5) + arow;
  #pragma unroll
  for (int r = 0; r < 16; ++r) {
    int row = (r & 3) + ((r >> 2) << 3) + (ahalf << 2);
    c_enc[((size_t)(enc * B_TOT + r0 + row) << 9) + col] = c_reg[r];
  }
}

// ---------------- decoder: chain 0 = speed head, chain 1 = crossing head -----
__global__ __launch_bounds__(1024) void lstm_decoder(
    const float* __restrict__ speed, const float* __restrict__ pos,
    const unsigned char* __restrict__ wpack8,
    const short* __restrict__ h_enc, const float* __restrict__ c_enc,
    const float* __restrict__ W_fs, const float* __restrict__ b_fs,
    const float* __restrict__ W_fc, const float* __restrict__ b_fc,
    const float* __restrict__ W_emb, const float* __restrict__ b_emb,
    float* __restrict__ out)
{
  __shared__ short hl[NROW * LROW];
  int tid = threadIdx.x;
  int b = blockIdx.x;
  int xcd = b & 7, slot = b >> 3;
  int chain = xcd >> 2;
  int rg = slot * 4 + (xcd & 3);
  int r0 = rg * 32;
  const unsigned char* wm8 = wpack8 + (size_t)chain * WMAT8_BYTES;

  for (int i = tid; i < NROW * LROW; i += 1024) hl[i] = 0;
  __syncthreads();
  for (int i = tid; i < 32 * 512; i += 1024) {
    int r = i >> 9, k = i & 511;
    float h0 = bf2f((unsigned short)h_enc[((size_t)(r0 + r) << 9) + k])
             + bf2f((unsigned short)h_enc[((size_t)(B_TOT + r0 + r) << 9) + k]);
    hl[r * LROW + k] = (short)f2bf(h0);
  }
  if (tid < 32) hl[tid * LROW + 516] = (short)0x3F80;
  {
    const float* last = chain ? pos : speed;
    if (tid < 128) {
      int r = tid >> 2, c = tid & 3;
      hl[r * LROW + 512 + c] = (short)f2bf(last[(r0 + r) * 64 + 60 + c]); // x[:,15,:]
    }
  }
  int lane = tid & 63, wv = tid >> 6;   // wv in [0,16)
  int arow = lane & 31, ahalf = lane >> 5;
  float c_reg[16];
  {
    int col = (wv << 5) + arow;
    #pragma unroll
    for (int r = 0; r < 16; ++r) {
      int row = (r & 3) + ((r >> 2) << 3) + (ahalf << 2);
      size_t gi = ((size_t)(r0 + row) << 9) + col;
      c_reg[r] = c_enc[gi] + c_enc[gi + (((size_t)B_TOT) << 9)];
    }
  }
  __syncthreads();

  float hnew[16];
  for (int t = 0; t < T_DEC; ++t) {
    lstm_step_mfma_fp8(hl, wm8, lane, wv, c_reg, hnew);
    __syncthreads();
    write_h(hl, lane, wv, hnew);
    __syncthreads();
    // heads: wave wv handles rows [wv*2, wv*2+2); 64 lanes x 8 k-elems = 512.
    for (int r = 0; r < 2; ++r) {
      int row = wv * 2 + r;
      const short8 hvs = *(const short8*)(hl + row * LROW + lane * 8);
      float hv[8];
      #pragma unroll
      for (int j = 0; j < 8; ++j) hv[j] = bf2f((unsigned short)hvs[j]);
      if (chain == 0) {
        float p0 = 0.f, p1 = 0.f, p2 = 0.f, p3 = 0.f;
        #pragma unroll
        for (int j = 0; j < 8; ++j) {
          p0 += hv[j] * W_fs[0 * 512 + lane * 8 + j];
          p1 += hv[j] * W_fs[1 * 512 + lane * 8 + j];
          p2 += hv[j] * W_fs[2 * 512 + lane * 8 + j];
          p3 += hv[j] * W_fs[3 * 512 + lane * 8 + j];
        }
        #pragma unroll
        for (int off = 32; off > 0; off >>= 1) {
          p0 += __shfl_xor(p0, off);
          p1 += __shfl_xor(p1, off);
          p2 += __shfl_xor(p2, off);
          p3 += __shfl_xor(p3, off);
        }
        float s0 = fminf(fmaxf(p0 + b_fs[0], -100.0f), 100.0f);
        float s1 = fminf(fmaxf(p1 + b_fs[1], -100.0f), 100.0f);
        float s2 = fminf(fmaxf(p2 + b_fs[2], -100.0f), 100.0f);
        float s3 = fminf(fmaxf(p3 + b_fs[3], -100.0f), 100.0f);
        if (lane < 4) {
          float v = (lane == 0) ? s0 : (lane == 1) ? s1 : (lane == 2) ? s2 : s3;
          out[(size_t)(r0 + row) * 128 + t * 4 + lane] = v;       // speed_outputs
          hl[row * LROW + 512 + lane] = (short)f2bf(v);           // ls feedback
        }
      } else {
        float p0 = 0.f, p1 = 0.f;
        #pragma unroll
        for (int j = 0; j < 8; ++j) {
          p0 += hv[j] * W_fc[0 * 512 + lane * 8 + j];
          p1 += hv[j] * W_fc[1 * 512 + lane * 8 + j];
        }
        #pragma unroll
        for (int off = 32; off > 0; off >>= 1) {
          p0 += __shfl_xor(p0, off);
          p1 += __shfl_xor(p1, off);
        }
        float it0 = fmaxf(p0 + b_fc[0], 0.0f);
        float it1 = fmaxf(p1 + b_fc[1], 0.0f);
        if (lane < 4) {
          float lp = fmaxf(W_emb[lane * 2] * it0 + W_emb[lane * 2 + 1] * it1 + b_emb[lane], 0.0f);
          hl[row * LROW + 512 + lane] = (short)f2bf(lp);          // lp feedback
        }
        if (t == T_DEC - 1 && lane < 2) {
          float m = fmaxf(it0, it1);
          float e0 = __expf(it0 - m), e1 = __expf(it1 - m);
          float v = ((lane == 0) ? e0 : e1) * rcpf(e0 + e1);
          out[(size_t)524288 + (size_t)(r0 + row) * 2 + lane] = v; // crossing
        }
      }
    }
    __syncthreads();
  }
}

extern "C" void kernel_launch(void* const* d_in, const int* in_sizes, int n_in,
                              void* d_out, int out_size, void* d_ws, size_t ws_size,
                              hipStream_t stream)
{
  const float* speed    = (const float*)d_in[0];
  const float* pos      = (const float*)d_in[1];
  const float* enc_s_Wi = (const float*)d_in[2];
  const float* enc_s_Wh = (const float*)d_in[3];
  const float* enc_s_b  = (const float*)d_in[4];
  const float* enc_p_Wi = (const float*)d_in[5];
  const float* enc_p_Wh = (const float*)d_in[6];
  const float* enc_p_b  = (const float*)d_in[7];
  const float* dec_s_Wi = (const float*)d_in[8];
  const float* dec_s_Wh = (const float*)d_in[9];
  const float* dec_s_b  = (const float*)d_in[10];
  const float* dec_i_Wi = (const float*)d_in[11];
  const float* dec_i_Wh = (const float*)d_in[12];
  const float* dec_i_b  = (const float*)d_in[13];
  const float* W_fs     = (const float*)d_in[14];
  const float* b_fs     = (const float*)d_in[15];
  const float* W_fc     = (const float*)d_in[16];
  const float* b_fc     = (const float*)d_in[17];
  const float* W_emb    = (const float*)d_in[18];
  const float* b_emb    = (const float*)d_in[19];
  float* out = (float*)d_out;

  char* ws = (char*)d_ws;
  short* wpack          = (short*)ws;                      // enc bf16: 2 x 2,162,688 B = 4,325,376 B
  unsigned char* wpack8 = (unsigned char*)(ws + 4325376);  // dec fp8:  2 x 1,081,344 B = 2,162,688 B
  short* h_enc          = (short*)(ws + 6488064);          // 2 x 4096 x 512 bf16 = 8,388,608 B
  float* c_enc          = (float*)(ws + 14876672);         // 2 x 4096 x 512 f32  = 16,777,216 B

  prep_weights<<<8448, 256, 0, stream>>>(
      enc_s_Wh, enc_s_Wi, enc_s_b,
      enc_p_Wh, enc_p_Wi, enc_p_b,
      wpack);
  prep_fp8<<<8448, 256, 0, stream>>>(
      dec_s_Wh, dec_s_Wi, dec_s_b,
      dec_i_Wh, dec_i_Wi, dec_i_b,
      wpack8);
  lstm_encoder<<<256, 1024, 0, stream>>>(speed, pos, wpack, h_enc, c_enc);
  lstm_decoder<<<256, 1024, 0, stream>>>(speed, pos, wpack8, h_enc, c_enc,
                                         W_fs, b_fs, W_fc, b_fc, W_emb, b_emb, out);
}